// Round 2
// baseline (341.467 us; speedup 1.0000x reference)
//
#include <hip/hip_runtime.h>
#include <hip/hip_bf16.h>

typedef __hip_bfloat16 bf16;
typedef __attribute__((ext_vector_type(8))) short bfrag;   // 8 bf16 in 4 VGPRs
typedef __attribute__((ext_vector_type(4))) float f32x4;

#define MFMA(a, b, c) __builtin_amdgcn_mfma_f32_16x16x32_bf16((a), (b), (c), 0, 0, 0)

// async global->LDS, 16B per lane; LDS dest = wave-uniform base + lane*16
__device__ __forceinline__ void async16(const void* g, void* l) {
  __builtin_amdgcn_global_load_lds(
      (const __attribute__((address_space(1))) unsigned int*)g,
      (__attribute__((address_space(3))) unsigned int*)l, 16, 0, 0);
}

__device__ __forceinline__ bfrag ldfrag(const bf16* p) { return *(const bfrag*)p; }

__device__ __forceinline__ unsigned short f2b(float f) {
  return __hip_bfloat16_raw(__float2bfloat16(f)).x;
}

// ---------------- prep kernels ----------------

__global__ void k_tables(const float* __restrict__ rp, float* __restrict__ ctab,
                         float* __restrict__ stab) {
  int i = blockIdx.x * 256 + threadIdx.x;   // 0..32767  (S*32)
  float f = rp[i];
  ctab[i] = cosf(f);
  stab[i] = sinf(f);
}

// X f32 -> bf16
__global__ void k_convert_x(const float* __restrict__ X, unsigned short* __restrict__ Xb) {
  int i = blockIdx.x * 256 + threadIdx.x;   // 0..2M-1, 4 elems each
  float4 v = *(const float4*)(X + i * 4);
  union { unsigned short h[4]; uint2 u; } pk;
  pk.h[0] = f2b(v.x); pk.h[1] = f2b(v.y); pk.h[2] = f2b(v.z); pk.h[3] = f2b(v.w);
  *(uint2*)(Xb + i * 4) = pk.u;
}

// w f32 (K=1024 x N=1024) row-major -> wT bf16 (N x K) row-major
__global__ void k_transpose_w(const float* __restrict__ wq, const float* __restrict__ wk,
                              const float* __restrict__ wv, const float* __restrict__ wo,
                              unsigned short* __restrict__ tq, unsigned short* __restrict__ tk,
                              unsigned short* __restrict__ tv, unsigned short* __restrict__ to) {
  const int z = blockIdx.z;
  const float* src = (z == 0) ? wq : (z == 1) ? wk : (z == 2) ? wv : wo;
  unsigned short* dst = (z == 0) ? tq : (z == 1) ? tk : (z == 2) ? tv : to;
  const int cc = blockIdx.x * 256 + threadIdx.x;  // column 0..1023 (coalesced reads)
  const int r0 = blockIdx.y * 8;
  union { unsigned short h[8]; uint4 u; } pk;
#pragma unroll
  for (int i = 0; i < 8; i++) pk.h[i] = f2b(src[(r0 + i) * 1024 + cc]);
  *(uint4*)(dst + cc * 1024 + r0) = pk.u;  // 16B store
}

// V[(b*S+s)][h*64+d] (bf16) -> VT[(bh*64+d)][s] (bf16)
__global__ void k_transpose_v(const unsigned short* __restrict__ V,
                              unsigned short* __restrict__ VT) {
  const int bh = blockIdx.y;
  const int b = bh >> 4, h = bh & 15;
  const int d = threadIdx.x & 63;
  const int sg = threadIdx.x >> 6;
  const int s0 = blockIdx.x * 32 + sg * 8;
  union { unsigned short h[8]; uint4 u; } pk;
#pragma unroll
  for (int i = 0; i < 8; i++)
    pk.h[i] = V[(size_t)(b * 1024 + s0 + i) * 1024 + h * 64 + d];
  *(uint4*)(VT + (size_t)(bh * 64 + d) * 1024 + s0) = pk.u;
}

// ---------------- GEMM (m97 structure): C = A @ BT^T + bias ----------------
// A: (8192 x 1024) bf16 row-major; BT: (1024 x 1024) bf16 row-major (N x K)
// ROPE: fused rotary on f32 acc before bf16 store. F32OUT: store float C.

template <bool ROPE, bool F32OUT>
__device__ __forceinline__ void gemm_core(const bf16* __restrict__ A,
                                          const bf16* __restrict__ BT,
                                          const float* __restrict__ bias,
                                          bf16* __restrict__ C, float* __restrict__ Cf,
                                          const float* __restrict__ ctab,
                                          const float* __restrict__ stab) {
  __shared__ __align__(16) bf16 As[128 * 32];
  __shared__ __align__(16) bf16 Bs[128 * 32];
  const int m0 = blockIdx.x * 128;
  const int n0 = blockIdx.y * 128;
  const int tid = threadIdx.x;
  const int w = tid >> 6, l = tid & 63;
  const int wm = (w >> 1) << 6, wn = (w & 1) << 6;  // 2x2 waves over 128x128
  const int c = l & 15, quad = l >> 4;

  f32x4 acc[4][4] = {};

  // staging: wave w stages 16-row chunks {2w,2w+1}; lane l -> row l/4, col (l%4)*8
  const int srow = (w * 2) * 16 + (l >> 2);
  const int scol = (l & 3) * 8;
  const bf16* gA0 = A + (m0 + srow) * 1024 + scol;
  const bf16* gA1 = gA0 + 16 * 1024;
  const bf16* gB0 = BT + (n0 + srow) * 1024 + scol;
  const bf16* gB1 = gB0 + 16 * 1024;
  char* lA0 = (char*)As + (w * 2) * 1024;
  char* lB0 = (char*)Bs + (w * 2) * 1024;

  for (int k0 = 0; k0 < 1024; k0 += 32) {
    __syncthreads();
    async16(gA0 + k0, lA0);
    async16(gA1 + k0, lA0 + 1024);
    async16(gB0 + k0, lB0);
    async16(gB1 + k0, lB0 + 1024);
    __syncthreads();
    bfrag a[4], b[4];
#pragma unroll
    for (int i = 0; i < 4; i++) a[i] = ldfrag(&As[(wm + i * 16 + c) * 32 + quad * 8]);
#pragma unroll
    for (int j = 0; j < 4; j++) b[j] = ldfrag(&Bs[(wn + j * 16 + c) * 32 + quad * 8]);
#pragma unroll
    for (int i = 0; i < 4; i++)
#pragma unroll
      for (int j = 0; j < 4; j++) acc[i][j] = MFMA(a[i], b[j], acc[i][j]);
  }

  // epilogue: C row = quad*4+reg, col = lane&15  (verified m89/m91 layout)
#pragma unroll
  for (int i = 0; i < 4; i++) {
    const int mb = m0 + wm + i * 16 + quad * 4;
    if (!ROPE) {
#pragma unroll
      for (int j = 0; j < 4; j++) {
        const int n = n0 + wn + j * 16 + c;
        const float bb = bias[n];
#pragma unroll
        for (int r = 0; r < 4; r++) {
          if (F32OUT)
            Cf[(size_t)(mb + r) * 1024 + n] = acc[i][j][r] + bb;
          else
            C[(size_t)(mb + r) * 1024 + n] = __float2bfloat16(acc[i][j][r] + bb);
        }
      }
    } else {
      // wave spans 64 aligned cols (one head): d = j*16+c pairs with tile j+2 (d+32)
#pragma unroll
      for (int j = 0; j < 2; j++) {
        const int n1 = n0 + wn + j * 16 + c;
        const int n2 = n1 + 32;
        const int dl = j * 16 + c;  // 0..31
        const float b1 = bias[n1];
        const float b2 = bias[n2];
#pragma unroll
        for (int r = 0; r < 4; r++) {
          const int m = mb + r;
          const int s = m & 1023;
          const float cs = ctab[s * 32 + dl];
          const float sn = stab[s * 32 + dl];
          const float t1 = acc[i][j][r] + b1;
          const float t2 = acc[i][j + 2][r] + b2;
          C[(size_t)m * 1024 + n1] = __float2bfloat16(t1 * cs - t2 * sn);  // d < 32
          C[(size_t)m * 1024 + n2] = __float2bfloat16(t2 * cs + t1 * sn);  // d >= 32
        }
      }
    }
  }
}

__global__ __launch_bounds__(256) void k_gemm_qkv(
    const bf16* __restrict__ X, const bf16* __restrict__ wqT, const bf16* __restrict__ wkT,
    const bf16* __restrict__ wvT, const float* __restrict__ bq, const float* __restrict__ bk,
    const float* __restrict__ bv, const float* __restrict__ ctab,
    const float* __restrict__ stab, bf16* __restrict__ Q, bf16* __restrict__ Kb,
    bf16* __restrict__ V) {
  const int z = blockIdx.z;
  const bf16* BT = (z == 0) ? wqT : (z == 1) ? wkT : wvT;
  const float* bias = (z == 0) ? bq : (z == 1) ? bk : bv;
  bf16* C = (z == 0) ? Q : (z == 1) ? Kb : V;
  if (z < 2)
    gemm_core<true, false>(X, BT, bias, C, nullptr, ctab, stab);
  else
    gemm_core<false, false>(X, BT, bias, C, nullptr, nullptr, nullptr);
}

__global__ __launch_bounds__(256) void k_gemm_o(const bf16* __restrict__ A,
                                                const bf16* __restrict__ BT,
                                                const float* __restrict__ bias,
                                                float* __restrict__ Cf) {
  gemm_core<false, true>(A, BT, bias, nullptr, Cf, nullptr, nullptr);
}

// ---------------- flash attention ----------------
// grid: (qt 0..15, bh 0..127). block = 256 = 4 waves; wave w owns q rows qt*64+w*16..+15.

__global__ __launch_bounds__(256) void k_flash(const bf16* __restrict__ Q,
                                               const bf16* __restrict__ K,
                                               const bf16* __restrict__ VT,
                                               bf16* __restrict__ O) {
  __shared__ __align__(16) bf16 Ks[64 * 64];      // [key][d]
  __shared__ __align__(16) bf16 Vs[64 * 64];      // [d][key]  (from VT)
  __shared__ __align__(16) bf16 Ps[4][16 * 72];   // per-wave P, row stride 72 (16B-aligned rows)
  const int qt = blockIdx.x, bh = blockIdx.y;
  const int b = bh >> 4, h = bh & 15;
  const int tid = threadIdx.x, w = tid >> 6, l = tid & 63;
  const int c = l & 15, quad = l >> 4;

  // Q A-frags kept in registers: m = lane&15, k(d) = quad*8..
  const bf16* qptr = Q + (size_t)(b * 1024 + qt * 64 + w * 16 + c) * 1024 + h * 64 + quad * 8;
  const bfrag qf0 = ldfrag(qptr);
  const bfrag qf1 = ldfrag(qptr + 32);

  f32x4 oacc[4] = {};
  float mrun[4], lrun[4];
#pragma unroll
  for (int r = 0; r < 4; r++) { mrun[r] = -1e30f; lrun[r] = 0.0f; }

  // staging: wave w stages 8-row chunks {2w,2w+1}; lane covers row l/8, col (l%8)*8
  const int srow = (w * 2) * 8 + (l >> 3);
  const int scol = (l & 7) * 8;
  const bf16* gK = K + (size_t)(b * 1024 + srow) * 1024 + h * 64 + scol;
  const bf16* gV = VT + (size_t)(bh * 64 + srow) * 1024 + scol;
  char* lK0 = (char*)Ks + (w * 2) * 1024;
  char* lV0 = (char*)Vs + (w * 2) * 1024;

  const float scale = 0.125f;  // 1/sqrt(64)

  for (int kt = 0; kt < 16; kt++) {
    __syncthreads();
    async16(gK + (size_t)(kt * 64) * 1024, lK0);
    async16(gK + (size_t)(kt * 64 + 8) * 1024, lK0 + 1024);
    async16(gV + kt * 64, lV0);
    async16(gV + 8 * 1024 + kt * 64, lV0 + 1024);
    __syncthreads();

    // S = Q @ K^T : B-frag rows are keys
    f32x4 sacc[4] = {};
#pragma unroll
    for (int nj = 0; nj < 4; nj++) {
      bfrag k0 = ldfrag(&Ks[(nj * 16 + c) * 64 + quad * 8]);
      bfrag k1 = ldfrag(&Ks[(nj * 16 + c) * 64 + 32 + quad * 8]);
      sacc[nj] = MFMA(qf0, k0, sacc[nj]);
      sacc[nj] = MFMA(qf1, k1, sacc[nj]);
    }

    // online softmax; row = quad*4+r, 16 lanes (c) share a row
    float mnew[4], alpha[4], rsum[4];
#pragma unroll
    for (int r = 0; r < 4; r++) {
      float mx = fmaxf(fmaxf(sacc[0][r], sacc[1][r]), fmaxf(sacc[2][r], sacc[3][r]));
      mx *= scale;
#pragma unroll
      for (int off = 1; off < 16; off <<= 1) mx = fmaxf(mx, __shfl_xor(mx, off, 64));
      mnew[r] = fmaxf(mrun[r], mx);
      alpha[r] = __expf(mrun[r] - mnew[r]);
      mrun[r] = mnew[r];
      rsum[r] = 0.0f;
    }
#pragma unroll
    for (int nj = 0; nj < 4; nj++) {
#pragma unroll
      for (int r = 0; r < 4; r++) {
        float p = __expf(sacc[nj][r] * scale - mnew[r]);
        rsum[r] += p;
        Ps[w][(quad * 4 + r) * 72 + nj * 16 + c] = __float2bfloat16(p);
      }
    }
#pragma unroll
    for (int r = 0; r < 4; r++) {
      float rs = rsum[r];
#pragma unroll
      for (int off = 1; off < 16; off <<= 1) rs += __shfl_xor(rs, off, 64);
      lrun[r] = lrun[r] * alpha[r] + rs;
      oacc[0][r] *= alpha[r];
      oacc[1][r] *= alpha[r];
      oacc[2][r] *= alpha[r];
      oacc[3][r] *= alpha[r];
    }

    // O += P @ V : P as A-operand (LDS round-trip), V^T rows from Vs
    bfrag p0 = ldfrag(&Ps[w][c * 72 + quad * 8]);
    bfrag p1 = ldfrag(&Ps[w][c * 72 + 32 + quad * 8]);
#pragma unroll
    for (int dj = 0; dj < 4; dj++) {
      bfrag v0 = ldfrag(&Vs[(dj * 16 + c) * 64 + quad * 8]);
      bfrag v1 = ldfrag(&Vs[(dj * 16 + c) * 64 + 32 + quad * 8]);
      oacc[dj] = MFMA(p0, v0, oacc[dj]);
      oacc[dj] = MFMA(p1, v1, oacc[dj]);
    }
  }

#pragma unroll
  for (int dj = 0; dj < 4; dj++) {
#pragma unroll
    for (int r = 0; r < 4; r++) {
      const float inv = 1.0f / lrun[r];
      const int q = qt * 64 + w * 16 + quad * 4 + r;
      O[(size_t)(b * 1024 + q) * 1024 + h * 64 + dj * 16 + c] =
          __float2bfloat16(oacc[dj][r] * inv);
    }
  }
}

// ---------------- launch ----------------

extern "C" void kernel_launch(void* const* d_in, const int* in_sizes, int n_in,
                              void* d_out, int out_size, void* d_ws, size_t ws_size,
                              hipStream_t stream) {
  const float* X  = (const float*)d_in[0];
  const float* rp = (const float*)d_in[1];
  const float* wq = (const float*)d_in[2];
  const float* bq = (const float*)d_in[3];
  const float* wk = (const float*)d_in[4];
  const float* bk = (const float*)d_in[5];
  const float* wv = (const float*)d_in[6];
  const float* bv = (const float*)d_in[7];
  const float* wo = (const float*)d_in[8];
  const float* bo = (const float*)d_in[9];
  float* out = (float*)d_out;

  char* ws = (char*)d_ws;
  const size_t MB = 1024 * 1024;
  bf16* Xb  = (bf16*)(ws + 0 * MB);    // 16 MB each
  bf16* Q   = (bf16*)(ws + 16 * MB);
  bf16* Kb  = (bf16*)(ws + 32 * MB);
  bf16* V   = (bf16*)(ws + 48 * MB);
  bf16* VT  = (bf16*)(ws + 64 * MB);
  bf16* O   = (bf16*)(ws + 48 * MB);   // alias: V dead after k_transpose_v
  bf16* wqT = (bf16*)(ws + 80 * MB);   // 2 MB each
  bf16* wkT = (bf16*)(ws + 82 * MB);
  bf16* wvT = (bf16*)(ws + 84 * MB);
  bf16* woT = (bf16*)(ws + 86 * MB);
  float* ctab = (float*)(ws + 88 * MB);  // 128 KB
  float* stab = ctab + 1024 * 32;        // 128 KB

  k_tables<<<dim3(128), dim3(256), 0, stream>>>(rp, ctab, stab);
  k_convert_x<<<dim3(8192), dim3(256), 0, stream>>>(X, (unsigned short*)Xb);
  k_transpose_w<<<dim3(4, 128, 4), dim3(256), 0, stream>>>(
      wq, wk, wv, wo, (unsigned short*)wqT, (unsigned short*)wkT, (unsigned short*)wvT,
      (unsigned short*)woT);
  k_gemm_qkv<<<dim3(64, 8, 3), dim3(256), 0, stream>>>(Xb, wqT, wkT, wvT, bq, bk, bv, ctab,
                                                       stab, Q, Kb, V);
  k_transpose_v<<<dim3(32, 128), dim3(256), 0, stream>>>((const unsigned short*)V,
                                                         (unsigned short*)VT);
  k_flash<<<dim3(16, 128), dim3(256), 0, stream>>>(Q, Kb, VT, O);
  k_gemm_o<<<dim3(64, 8, 1), dim3(256), 0, stream>>>(O, woT, bo, out);
}

// Round 3
// 257.342 us; speedup vs baseline: 1.3269x; 1.3269x over previous
//
#include <hip/hip_runtime.h>
#include <hip/hip_bf16.h>

typedef __hip_bfloat16 bf16;
typedef __attribute__((ext_vector_type(8))) short bfrag;   // 8 bf16 in 4 VGPRs
typedef __attribute__((ext_vector_type(4))) float f32x4;

#define MFMA(a, b, c) __builtin_amdgcn_mfma_f32_16x16x32_bf16((a), (b), (c), 0, 0, 0)

// async global->LDS, 16B per lane; LDS dest = wave-uniform base + lane*16
__device__ __forceinline__ void async16(const void* g, void* l) {
  __builtin_amdgcn_global_load_lds(
      (const __attribute__((address_space(1))) unsigned int*)g,
      (__attribute__((address_space(3))) unsigned int*)l, 16, 0, 0);
}

__device__ __forceinline__ bfrag ldfrag(const bf16* p) { return *(const bfrag*)p; }

__device__ __forceinline__ unsigned short f2b(float f) {
  return __hip_bfloat16_raw(__float2bfloat16(f)).x;
}
__device__ __forceinline__ float b2f(short u) {
  __hip_bfloat16_raw r; r.x = (unsigned short)u;
  return __bfloat162float(__hip_bfloat16(r));
}

// multiply a bf16 frag by 0.125 (exact: power of two)
__device__ __forceinline__ bfrag scale8(bfrag x) {
  bfrag y;
#pragma unroll
  for (int i = 0; i < 8; i++) y[i] = (short)f2b(b2f(x[i]) * 0.125f);
  return y;
}

__device__ __forceinline__ void pack4_store(bf16* p, f32x4 v, float s) {
  union { unsigned short h[4]; uint2 u; } pk;
#pragma unroll
  for (int i = 0; i < 4; i++) pk.h[i] = f2b(v[i] * s);
  *(uint2*)p = pk.u;
}

// ---------------- prep kernels ----------------

__global__ void k_tables(const float* __restrict__ rp, float* __restrict__ ctab,
                         float* __restrict__ stab) {
  int i = blockIdx.x * 256 + threadIdx.x;   // 0..32767  (S*32)
  float f = rp[i];
  ctab[i] = cosf(f);
  stab[i] = sinf(f);
}

// X f32 -> bf16
__global__ void k_convert_x(const float* __restrict__ X, unsigned short* __restrict__ Xb) {
  int i = blockIdx.x * 256 + threadIdx.x;   // 4 elems each
  float4 v = *(const float4*)(X + (size_t)i * 4);
  union { unsigned short h[4]; uint2 u; } pk;
  pk.h[0] = f2b(v.x); pk.h[1] = f2b(v.y); pk.h[2] = f2b(v.z); pk.h[3] = f2b(v.w);
  *(uint2*)(Xb + (size_t)i * 4) = pk.u;
}

// w f32 (K=1024 x N=1024) row-major -> wT bf16 (N x K) row-major
__global__ void k_transpose_w(const float* __restrict__ wq, const float* __restrict__ wk,
                              const float* __restrict__ wv, const float* __restrict__ wo,
                              unsigned short* __restrict__ tq, unsigned short* __restrict__ tk,
                              unsigned short* __restrict__ tv, unsigned short* __restrict__ to) {
  const int z = blockIdx.z;
  const float* src = (z == 0) ? wq : (z == 1) ? wk : (z == 2) ? wv : wo;
  unsigned short* dst = (z == 0) ? tq : (z == 1) ? tk : (z == 2) ? tv : to;
  const int cc = blockIdx.x * 256 + threadIdx.x;  // column (coalesced reads)
  const int r0 = blockIdx.y * 8;
  union { unsigned short h[8]; uint4 u; } pk;
#pragma unroll
  for (int i = 0; i < 8; i++) pk.h[i] = f2b(src[(r0 + i) * 1024 + cc]);
  *(uint4*)(dst + cc * 1024 + r0) = pk.u;  // 16B store
}

// ---------------- GEMM (m97 structure): C = A @ BT^T + bias ----------------
// A: (M x 1024) bf16 row-major; BT: (N x 1024) bf16 row-major.
// ROPE: fused rotary. F32OUT: f32 C. BIAS_ROW: bias indexed by row (for V^T gemm).

template <bool ROPE, bool F32OUT, bool BIAS_ROW, int CSTRIDE>
__device__ __forceinline__ void gemm_core(int m0, int n0, const bf16* __restrict__ A,
                                          const bf16* __restrict__ BT,
                                          const float* __restrict__ bias,
                                          bf16* __restrict__ C, float* __restrict__ Cf,
                                          const float* __restrict__ ctab,
                                          const float* __restrict__ stab) {
  __shared__ __align__(16) bf16 As[128 * 32];
  __shared__ __align__(16) bf16 Bs[128 * 32];
  const int tid = threadIdx.x;
  const int w = tid >> 6, l = tid & 63;
  const int wm = (w >> 1) << 6, wn = (w & 1) << 6;  // 2x2 waves over 128x128
  const int c = l & 15, quad = l >> 4;

  f32x4 acc[4][4] = {};

  // staging: wave w stages 16-row chunks {2w,2w+1}; lane l -> row l/4, col (l%4)*8
  const int srow = (w * 2) * 16 + (l >> 2);
  const int scol = (l & 3) * 8;
  const bf16* gA0 = A + (size_t)(m0 + srow) * 1024 + scol;
  const bf16* gA1 = gA0 + 16 * 1024;
  const bf16* gB0 = BT + (size_t)(n0 + srow) * 1024 + scol;
  const bf16* gB1 = gB0 + 16 * 1024;
  char* lA0 = (char*)As + (w * 2) * 1024;
  char* lB0 = (char*)Bs + (w * 2) * 1024;

  for (int k0 = 0; k0 < 1024; k0 += 32) {
    __syncthreads();
    async16(gA0 + k0, lA0);
    async16(gA1 + k0, lA0 + 1024);
    async16(gB0 + k0, lB0);
    async16(gB1 + k0, lB0 + 1024);
    __syncthreads();
    bfrag a[4], b[4];
#pragma unroll
    for (int i = 0; i < 4; i++) a[i] = ldfrag(&As[(wm + i * 16 + c) * 32 + quad * 8]);
#pragma unroll
    for (int j = 0; j < 4; j++) b[j] = ldfrag(&Bs[(wn + j * 16 + c) * 32 + quad * 8]);
#pragma unroll
    for (int i = 0; i < 4; i++)
#pragma unroll
      for (int j = 0; j < 4; j++) acc[i][j] = MFMA(a[i], b[j], acc[i][j]);
  }

  // epilogue: C row = quad*4+reg, col = lane&15
#pragma unroll
  for (int i = 0; i < 4; i++) {
    const int mb = m0 + wm + i * 16 + quad * 4;
    if (!ROPE) {
      float brow[4];
      if (BIAS_ROW) {
#pragma unroll
        for (int r = 0; r < 4; r++) brow[r] = bias[mb + r];
      }
#pragma unroll
      for (int j = 0; j < 4; j++) {
        const int n = n0 + wn + j * 16 + c;
        const float bcol = BIAS_ROW ? 0.0f : bias[n];
#pragma unroll
        for (int r = 0; r < 4; r++) {
          const float val = acc[i][j][r] + (BIAS_ROW ? brow[r] : bcol);
          if (F32OUT)
            Cf[(size_t)(mb + r) * CSTRIDE + n] = val;
          else
            C[(size_t)(mb + r) * CSTRIDE + n] = __float2bfloat16(val);
        }
      }
    } else {
      // wave spans 64 aligned cols (one head): d = j*16+c pairs with tile j+2 (d+32)
#pragma unroll
      for (int j = 0; j < 2; j++) {
        const int n1 = n0 + wn + j * 16 + c;
        const int n2 = n1 + 32;
        const int dl = j * 16 + c;  // 0..31
        const float b1 = bias[n1];
        const float b2 = bias[n2];
#pragma unroll
        for (int r = 0; r < 4; r++) {
          const int m = mb + r;
          const int s = m & 1023;
          const float cs = ctab[s * 32 + dl];
          const float sn = stab[s * 32 + dl];
          const float t1 = acc[i][j][r] + b1;
          const float t2 = acc[i][j + 2][r] + b2;
          C[(size_t)m * CSTRIDE + n1] = __float2bfloat16(t1 * cs - t2 * sn);  // d < 32
          C[(size_t)m * CSTRIDE + n2] = __float2bfloat16(t2 * cs + t1 * sn);  // d >= 32
        }
      }
    }
  }
}

// z=0: Q (rope), z=1: K (rope), z=2: VT = Wv^T @ X^T  (1024 x 8192)
__global__ __launch_bounds__(256) void k_gemm_qkv(
    const bf16* __restrict__ X, const bf16* __restrict__ wqT, const bf16* __restrict__ wkT,
    const bf16* __restrict__ wvT, const float* __restrict__ bq, const float* __restrict__ bk,
    const float* __restrict__ bv, const float* __restrict__ ctab,
    const float* __restrict__ stab, bf16* __restrict__ Q, bf16* __restrict__ Kb,
    bf16* __restrict__ VT) {
  const int z = blockIdx.z;
  if (z == 0)
    gemm_core<true, false, false, 1024>(blockIdx.x * 128, blockIdx.y * 128, X, wqT, bq, Q,
                                        nullptr, ctab, stab);
  else if (z == 1)
    gemm_core<true, false, false, 1024>(blockIdx.x * 128, blockIdx.y * 128, X, wkT, bk, Kb,
                                        nullptr, ctab, stab);
  else
    gemm_core<false, false, true, 8192>(blockIdx.y * 128, blockIdx.x * 128, wvT, X, bv, VT,
                                        nullptr, nullptr, nullptr);
}

__global__ __launch_bounds__(256) void k_gemm_o(const bf16* __restrict__ A,
                                                const bf16* __restrict__ BT,
                                                const float* __restrict__ bias,
                                                float* __restrict__ Cf) {
  gemm_core<false, true, false, 1024>(blockIdx.x * 128, blockIdx.y * 128, A, BT, bias,
                                      nullptr, Cf, nullptr, nullptr);
}

// ---------------- flash attention (no-max online softmax, S^T/O^T form) -------
// grid: (qt 0..7, bh 0..127). block = 256 = 4 waves; wave w owns 32 q rows.
// VT: [1024 vcols][8192 s]  (vcol = h*64+d, s = b*1024+s')

__global__ __launch_bounds__(256, 4) void k_flash(const bf16* __restrict__ Q,
                                                  const bf16* __restrict__ K,
                                                  const bf16* __restrict__ VT,
                                                  bf16* __restrict__ O) {
  __shared__ __align__(16) bf16 Ks[64 * 64];     // [key][d], chunk-swizzled
  __shared__ __align__(16) bf16 Vs[64 * 64];     // [d][key], chunk-swizzled
  __shared__ __align__(16) bf16 Ps[4][32 * 72];  // per-wave P [qrow][key], stride 72
  const int qt = blockIdx.x, bh = blockIdx.y;
  const int b = bh >> 4, h = bh & 15;
  const int tid = threadIdx.x, w = tid >> 6, l = tid & 63;
  const int c = l & 15, quad = l >> 4;
  const int c7 = c & 7;

  // Q B-frags (n = q), pre-scaled by 1/8 (exact)
  bfrag qf[2][2];
#pragma unroll
  for (int qs = 0; qs < 2; qs++) {
    const bf16* qp =
        Q + (size_t)(b * 1024 + qt * 128 + w * 32 + qs * 16 + c) * 1024 + h * 64 + quad * 8;
    qf[qs][0] = scale8(ldfrag(qp));
    qf[qs][1] = scale8(ldfrag(qp + 32));
  }

  bfrag onesf;
#pragma unroll
  for (int i = 0; i < 8; i++) onesf[i] = (short)0x3F80;  // 1.0 bf16

  f32x4 oacc[2][4] = {};  // O^T: [qs][dj], row d = dj*16+quad*4+r, col q
  f32x4 lacc[2] = {};     // row sums l[q]

  // staging: wave w covers rows w*16+sr and +8; global chunk xor-swizzled by row&7
  const int sr = l >> 3, scc = l & 7;
  const int swz = (scc ^ sr) * 8;
  const bf16* gK0 = K + (size_t)(b * 1024 + w * 16 + sr) * 1024 + h * 64 + swz;
  const bf16* gV0 = VT + (size_t)(h * 64 + w * 16 + sr) * 8192 + b * 1024 + swz;
  char* lK = (char*)Ks + w * 2048;
  char* lV = (char*)Vs + w * 2048;
  bf16* psw = Ps[w];

  for (int kt = 0; kt < 16; kt++) {
    __syncthreads();
    async16(gK0 + (size_t)(kt * 64) * 1024, lK);
    async16(gK0 + (size_t)(kt * 64 + 8) * 1024, lK + 1024);
    async16(gV0 + kt * 64, lV);
    async16(gV0 + 8 * 8192 + kt * 64, lV + 1024);
    __syncthreads();

    // S^T = K @ Q^T : A = K (m = key), B = Q^T. C row = key, col = q.
#pragma unroll
    for (int qs = 0; qs < 2; qs++) {
      f32x4 sacc[4] = {};
#pragma unroll
      for (int mj = 0; mj < 4; mj++) {
        bfrag k0 = ldfrag(&Ks[(mj * 16 + c) * 64 + (quad ^ c7) * 8]);
        bfrag k1 = ldfrag(&Ks[(mj * 16 + c) * 64 + ((quad + 4) ^ c7) * 8]);
        sacc[mj] = MFMA(k0, qf[qs][0], sacc[mj]);
        sacc[mj] = MFMA(k1, qf[qs][1], sacc[mj]);
      }
      // p = exp(s) (scores bounded ~|15|, safe in f32); pack 4 keys -> b64
      const int psrow = (qs * 16 + c) * 72;
#pragma unroll
      for (int mj = 0; mj < 4; mj++) {
        f32x4 p;
#pragma unroll
        for (int r = 0; r < 4; r++) p[r] = __expf(sacc[mj][r]);
        pack4_store(&psw[psrow + mj * 16 + quad * 4], p, 1.0f);
      }
    }

    // O^T += V^T @ P^T ; l += 1 @ P^T
    bfrag pf[2][2];
#pragma unroll
    for (int qs = 0; qs < 2; qs++) {
      pf[qs][0] = ldfrag(&psw[(qs * 16 + c) * 72 + quad * 8]);
      pf[qs][1] = ldfrag(&psw[(qs * 16 + c) * 72 + 32 + quad * 8]);
      lacc[qs] = MFMA(onesf, pf[qs][0], lacc[qs]);
      lacc[qs] = MFMA(onesf, pf[qs][1], lacc[qs]);
    }
#pragma unroll
    for (int dj = 0; dj < 4; dj++) {
      bfrag v0 = ldfrag(&Vs[(dj * 16 + c) * 64 + (quad ^ c7) * 8]);
      bfrag v1 = ldfrag(&Vs[(dj * 16 + c) * 64 + ((quad + 4) ^ c7) * 8]);
#pragma unroll
      for (int qs = 0; qs < 2; qs++) {
        oacc[qs][dj] = MFMA(v0, pf[qs][0], oacc[qs][dj]);
        oacc[qs][dj] = MFMA(v1, pf[qs][1], oacc[qs][dj]);
      }
    }
  }

  // O[q][h*64+d] = O^T / l ; pack 4 contiguous d -> 8B stores
#pragma unroll
  for (int qs = 0; qs < 2; qs++) {
    const float inv = 1.0f / lacc[qs][0];
    bf16* op =
        O + (size_t)(b * 1024 + qt * 128 + w * 32 + qs * 16 + c) * 1024 + h * 64 + quad * 4;
#pragma unroll
    for (int dj = 0; dj < 4; dj++) pack4_store(op + dj * 16, oacc[qs][dj], inv);
  }
}

// ---------------- launch ----------------

extern "C" void kernel_launch(void* const* d_in, const int* in_sizes, int n_in,
                              void* d_out, int out_size, void* d_ws, size_t ws_size,
                              hipStream_t stream) {
  const float* X  = (const float*)d_in[0];
  const float* rp = (const float*)d_in[1];
  const float* wq = (const float*)d_in[2];
  const float* bq = (const float*)d_in[3];
  const float* wk = (const float*)d_in[4];
  const float* bk = (const float*)d_in[5];
  const float* wv = (const float*)d_in[6];
  const float* bv = (const float*)d_in[7];
  const float* wo = (const float*)d_in[8];
  const float* bo = (const float*)d_in[9];
  float* out = (float*)d_out;

  char* ws = (char*)d_ws;
  const size_t MB = 1024 * 1024;
  bf16* Xb  = (bf16*)(ws + 0 * MB);    // 16 MB each
  bf16* Q   = (bf16*)(ws + 16 * MB);
  bf16* Kb  = (bf16*)(ws + 32 * MB);
  bf16* VT  = (bf16*)(ws + 48 * MB);   // [1024][8192]
  bf16* O   = (bf16*)(ws + 64 * MB);
  bf16* wqT = (bf16*)(ws + 80 * MB);   // 2 MB each
  bf16* wkT = (bf16*)(ws + 82 * MB);
  bf16* wvT = (bf16*)(ws + 84 * MB);
  bf16* woT = (bf16*)(ws + 86 * MB);
  float* ctab = (float*)(ws + 88 * MB);  // 128 KB
  float* stab = ctab + 1024 * 32;        // 128 KB

  k_tables<<<dim3(128), dim3(256), 0, stream>>>(rp, ctab, stab);
  k_convert_x<<<dim3(8192), dim3(256), 0, stream>>>(X, (unsigned short*)Xb);
  k_transpose_w<<<dim3(4, 128, 4), dim3(256), 0, stream>>>(
      wq, wk, wv, wo, (unsigned short*)wqT, (unsigned short*)wkT, (unsigned short*)wvT,
      (unsigned short*)woT);
  k_gemm_qkv<<<dim3(64, 8, 3), dim3(256), 0, stream>>>(Xb, wqT, wkT, wvT, bq, bk, bv, ctab,
                                                       stab, Q, Kb, VT);
  k_flash<<<dim3(8, 128), dim3(256), 0, stream>>>(Q, Kb, VT, O);
  k_gemm_o<<<dim3(64, 8, 1), dim3(256), 0, stream>>>(O, woT, bo, out);
}

// Round 4
// 244.675 us; speedup vs baseline: 1.3956x; 1.0518x over previous
//
#include <hip/hip_runtime.h>
#include <hip/hip_bf16.h>

typedef __hip_bfloat16 bf16;
typedef __attribute__((ext_vector_type(8))) short bfrag;   // 8 bf16 in 4 VGPRs
typedef __attribute__((ext_vector_type(4))) float f32x4;

#define MFMA(a, b, c) __builtin_amdgcn_mfma_f32_16x16x32_bf16((a), (b), (c), 0, 0, 0)

// async global->LDS, 16B per lane; LDS dest = wave-uniform base + lane*16
__device__ __forceinline__ void async16(const void* g, void* l) {
  __builtin_amdgcn_global_load_lds(
      (const __attribute__((address_space(1))) unsigned int*)g,
      (__attribute__((address_space(3))) unsigned int*)l, 16, 0, 0);
}

__device__ __forceinline__ bfrag ldfrag(const bf16* p) { return *(const bfrag*)p; }

__device__ __forceinline__ unsigned short f2b(float f) {
  return __hip_bfloat16_raw(__float2bfloat16(f)).x;
}
__device__ __forceinline__ float b2f(short u) {
  __hip_bfloat16_raw r; r.x = (unsigned short)u;
  return __bfloat162float(__hip_bfloat16(r));
}

// multiply a bf16 frag by 0.125 (exact: power of two)
__device__ __forceinline__ bfrag scale8(bfrag x) {
  bfrag y;
#pragma unroll
  for (int i = 0; i < 8; i++) y[i] = (short)f2b(b2f(x[i]) * 0.125f);
  return y;
}

__device__ __forceinline__ void pack4_store(bf16* p, f32x4 v, float s) {
  union { unsigned short h[4]; uint2 u; } pk;
#pragma unroll
  for (int i = 0; i < 4; i++) pk.h[i] = f2b(v[i] * s);
  *(uint2*)p = pk.u;
}

// ---------------- prep kernels ----------------

__global__ void k_tables(const float* __restrict__ rp, float* __restrict__ ctab,
                         float* __restrict__ stab) {
  int i = blockIdx.x * 256 + threadIdx.x;   // 0..32767  (S*32)
  float f = rp[i];
  ctab[i] = cosf(f);
  stab[i] = sinf(f);
}

// X f32 -> bf16
__global__ void k_convert_x(const float* __restrict__ X, unsigned short* __restrict__ Xb) {
  int i = blockIdx.x * 256 + threadIdx.x;   // 4 elems each
  float4 v = *(const float4*)(X + (size_t)i * 4);
  union { unsigned short h[4]; uint2 u; } pk;
  pk.h[0] = f2b(v.x); pk.h[1] = f2b(v.y); pk.h[2] = f2b(v.z); pk.h[3] = f2b(v.w);
  *(uint2*)(Xb + (size_t)i * 4) = pk.u;
}

// w f32 (K=1024 x N=1024) row-major -> wT bf16 (N x K) row-major. LDS-tiled 64x64.
__global__ void k_transpose_w(const float* __restrict__ wq, const float* __restrict__ wk,
                              const float* __restrict__ wv, const float* __restrict__ wo,
                              unsigned short* __restrict__ tq, unsigned short* __restrict__ tk,
                              unsigned short* __restrict__ tv, unsigned short* __restrict__ to) {
  __shared__ unsigned short T[64][72];
  const int z = blockIdx.z;
  const float* src = (z == 0) ? wq : (z == 1) ? wk : (z == 2) ? wv : wo;
  unsigned short* dst = (z == 0) ? tq : (z == 1) ? tk : (z == 2) ? tv : to;
  const int k0 = blockIdx.y * 64, n0 = blockIdx.x * 64;
  const int t = threadIdx.x;
  const int kr = t >> 4;          // 0..15
  const int nc = (t & 15) * 4;    // 0..60
#pragma unroll
  for (int g = 0; g < 4; g++) {   // coalesced f32x4 reads
    float4 v = *(const float4*)(src + (size_t)(k0 + g * 16 + kr) * 1024 + n0 + nc);
    const int kk = g * 16 + kr;
    T[nc + 0][kk] = f2b(v.x);
    T[nc + 1][kk] = f2b(v.y);
    T[nc + 2][kk] = f2b(v.z);
    T[nc + 3][kk] = f2b(v.w);
  }
  __syncthreads();
  const int nr = t >> 2;          // 0..63
  const int kc = (t & 3) * 16;    // 16 bf16 = 2 x uint4 per thread
  unsigned short* dp = dst + (size_t)(n0 + nr) * 1024 + k0 + kc;
  *(uint4*)(dp + 0) = *(const uint4*)(&T[nr][kc + 0]);
  *(uint4*)(dp + 8) = *(const uint4*)(&T[nr][kc + 8]);
}

// ---------------- GEMM: C = A @ BT^T + bias, BK=64, XOR-swizzled LDS ----------
// A: (M x 1024) bf16 row-major; BT: (N x 1024) bf16 row-major.
// LDS layout: row stride 64 bf16 (128 B); 16B chunk p of row r holds global
// chunk p ^ (r & 7)  -> frag reads spread across all 32 banks (2-way = free).
// ROPE: fused rotary. F32OUT: f32 C. BIAS_ROW: bias indexed by row (VT gemm).

template <bool ROPE, bool F32OUT, bool BIAS_ROW, int CSTRIDE>
__device__ __forceinline__ void gemm_core(bf16* As, bf16* Bs, int m0, int n0,
                                          const bf16* __restrict__ A,
                                          const bf16* __restrict__ BT,
                                          const float* __restrict__ bias,
                                          bf16* __restrict__ C, float* __restrict__ Cf,
                                          const float* __restrict__ ctab,
                                          const float* __restrict__ stab) {
  const int tid = threadIdx.x;
  const int w = tid >> 6, l = tid & 63;
  const int wm = (w >> 1) << 6, wn = (w & 1) << 6;  // 2x2 waves over 128x128
  const int c = l & 15, quad = l >> 4;
  const int c7 = c & 7;

  f32x4 acc[4][4] = {};

  // staging: wave w stages rows w*32..w*32+31 in 4 groups of 8 rows.
  // lane l -> local row rl = l>>3, phys chunk ch = l&7, global chunk = ch ^ rl.
  const int rl = l >> 3, ch = l & 7;
  const int sc = ((ch ^ rl) * 8);
  const bf16* gA = A + (size_t)(m0 + w * 32 + rl) * 1024 + sc;
  const bf16* gB = BT + (size_t)(n0 + w * 32 + rl) * 1024 + sc;
  char* lA = (char*)As + w * 32 * 128;
  char* lB = (char*)Bs + w * 32 * 128;

  for (int k0 = 0; k0 < 1024; k0 += 64) {
    __syncthreads();
#pragma unroll
    for (int g = 0; g < 4; g++) {
      async16(gA + (size_t)g * 8 * 1024 + k0, lA + g * 1024);
      async16(gB + (size_t)g * 8 * 1024 + k0, lB + g * 1024);
    }
    __syncthreads();
#pragma unroll
    for (int ks = 0; ks < 2; ks++) {
      bfrag a[4], b[4];
#pragma unroll
      for (int i = 0; i < 4; i++)
        a[i] = ldfrag(&As[(wm + i * 16 + c) * 64 + (((ks * 4 + quad) ^ c7) * 8)]);
#pragma unroll
      for (int j = 0; j < 4; j++)
        b[j] = ldfrag(&Bs[(wn + j * 16 + c) * 64 + (((ks * 4 + quad) ^ c7) * 8)]);
#pragma unroll
      for (int i = 0; i < 4; i++)
#pragma unroll
        for (int j = 0; j < 4; j++) acc[i][j] = MFMA(a[i], b[j], acc[i][j]);
    }
  }

  // epilogue: C row = quad*4+reg, col = lane&15
#pragma unroll
  for (int i = 0; i < 4; i++) {
    const int mb = m0 + wm + i * 16 + quad * 4;
    if (!ROPE) {
      float brow[4];
      if (BIAS_ROW) {
#pragma unroll
        for (int r = 0; r < 4; r++) brow[r] = bias[mb + r];
      }
#pragma unroll
      for (int j = 0; j < 4; j++) {
        const int n = n0 + wn + j * 16 + c;
        const float bcol = BIAS_ROW ? 0.0f : bias[n];
#pragma unroll
        for (int r = 0; r < 4; r++) {
          const float val = acc[i][j][r] + (BIAS_ROW ? brow[r] : bcol);
          if (F32OUT)
            Cf[(size_t)(mb + r) * CSTRIDE + n] = val;
          else
            C[(size_t)(mb + r) * CSTRIDE + n] = __float2bfloat16(val);
        }
      }
    } else {
      // wave spans 64 aligned cols (one head): d = j*16+c pairs with tile j+2 (d+32)
#pragma unroll
      for (int j = 0; j < 2; j++) {
        const int n1 = n0 + wn + j * 16 + c;
        const int n2 = n1 + 32;
        const int dl = j * 16 + c;  // 0..31
        const float b1 = bias[n1];
        const float b2 = bias[n2];
#pragma unroll
        for (int r = 0; r < 4; r++) {
          const int m = mb + r;
          const int s = m & 1023;
          const float cs = ctab[s * 32 + dl];
          const float sn = stab[s * 32 + dl];
          const float t1 = acc[i][j][r] + b1;
          const float t2 = acc[i][j + 2][r] + b2;
          C[(size_t)m * CSTRIDE + n1] = __float2bfloat16(t1 * cs - t2 * sn);  // d < 32
          C[(size_t)m * CSTRIDE + n2] = __float2bfloat16(t2 * cs + t1 * sn);  // d >= 32
        }
      }
    }
  }
}

// z=0: Q (rope), z=1: K (rope), z=2: VT = Wv^T @ X^T  (1024 x 8192)
__global__ __launch_bounds__(256) void k_gemm_qkv(
    const bf16* __restrict__ X, const bf16* __restrict__ wqT, const bf16* __restrict__ wkT,
    const bf16* __restrict__ wvT, const float* __restrict__ bq, const float* __restrict__ bk,
    const float* __restrict__ bv, const float* __restrict__ ctab,
    const float* __restrict__ stab, bf16* __restrict__ Q, bf16* __restrict__ Kb,
    bf16* __restrict__ VT) {
  __shared__ __align__(16) bf16 As[128 * 64];
  __shared__ __align__(16) bf16 Bs[128 * 64];
  const int z = blockIdx.z;
  if (z == 0)
    gemm_core<true, false, false, 1024>(As, Bs, blockIdx.x * 128, blockIdx.y * 128, X, wqT,
                                        bq, Q, nullptr, ctab, stab);
  else if (z == 1)
    gemm_core<true, false, false, 1024>(As, Bs, blockIdx.x * 128, blockIdx.y * 128, X, wkT,
                                        bk, Kb, nullptr, ctab, stab);
  else
    gemm_core<false, false, true, 8192>(As, Bs, blockIdx.y * 128, blockIdx.x * 128, wvT, X,
                                        bv, VT, nullptr, nullptr, nullptr);
}

__global__ __launch_bounds__(256) void k_gemm_o(const bf16* __restrict__ A,
                                                const bf16* __restrict__ BT,
                                                const float* __restrict__ bias,
                                                float* __restrict__ Cf) {
  __shared__ __align__(16) bf16 As[128 * 64];
  __shared__ __align__(16) bf16 Bs[128 * 64];
  gemm_core<false, true, false, 1024>(As, Bs, blockIdx.x * 128, blockIdx.y * 128, A, BT,
                                      bias, nullptr, Cf, nullptr, nullptr);
}

// ---------------- flash attention (no-max online softmax, S^T/O^T form) -------
// grid: (qt 0..7, bh 0..127). block = 256 = 4 waves; wave w owns 32 q rows.
// VT: [1024 vcols][8192 s]  (vcol = h*64+d, s = b*1024+s')

__global__ __launch_bounds__(256, 4) void k_flash(const bf16* __restrict__ Q,
                                                  const bf16* __restrict__ K,
                                                  const bf16* __restrict__ VT,
                                                  bf16* __restrict__ O) {
  __shared__ __align__(16) bf16 Ks[64 * 64];     // [key][d], chunk-swizzled
  __shared__ __align__(16) bf16 Vs[64 * 64];     // [d][key], chunk-swizzled
  __shared__ __align__(16) bf16 Ps[4][32 * 72];  // per-wave P [qrow][key], stride 72
  const int qt = blockIdx.x, bh = blockIdx.y;
  const int b = bh >> 4, h = bh & 15;
  const int tid = threadIdx.x, w = tid >> 6, l = tid & 63;
  const int c = l & 15, quad = l >> 4;
  const int c7 = c & 7;

  // Q B-frags (n = q), pre-scaled by 1/8 (exact)
  bfrag qf[2][2];
#pragma unroll
  for (int qs = 0; qs < 2; qs++) {
    const bf16* qp =
        Q + (size_t)(b * 1024 + qt * 128 + w * 32 + qs * 16 + c) * 1024 + h * 64 + quad * 8;
    qf[qs][0] = scale8(ldfrag(qp));
    qf[qs][1] = scale8(ldfrag(qp + 32));
  }

  bfrag onesf;
#pragma unroll
  for (int i = 0; i < 8; i++) onesf[i] = (short)0x3F80;  // 1.0 bf16

  f32x4 oacc[2][4] = {};  // O^T: [qs][dj], row d = dj*16+quad*4+r, col q
  f32x4 lacc[2] = {};     // row sums l[q]

  // staging: wave w covers rows w*16+sr and +8; global chunk xor-swizzled by row&7
  const int sr = l >> 3, scc = l & 7;
  const int swz = (scc ^ sr) * 8;
  const bf16* gK0 = K + (size_t)(b * 1024 + w * 16 + sr) * 1024 + h * 64 + swz;
  const bf16* gV0 = VT + (size_t)(h * 64 + w * 16 + sr) * 8192 + b * 1024 + swz;
  char* lK = (char*)Ks + w * 2048;
  char* lV = (char*)Vs + w * 2048;
  bf16* psw = Ps[w];

  for (int kt = 0; kt < 16; kt++) {
    __syncthreads();
    async16(gK0 + (size_t)(kt * 64) * 1024, lK);
    async16(gK0 + (size_t)(kt * 64 + 8) * 1024, lK + 1024);
    async16(gV0 + kt * 64, lV);
    async16(gV0 + 8 * 8192 + kt * 64, lV + 1024);
    __syncthreads();

    // S^T = K @ Q^T : A = K (m = key), B = Q^T. C row = key, col = q.
#pragma unroll
    for (int qs = 0; qs < 2; qs++) {
      f32x4 sacc[4] = {};
#pragma unroll
      for (int mj = 0; mj < 4; mj++) {
        bfrag k0 = ldfrag(&Ks[(mj * 16 + c) * 64 + (quad ^ c7) * 8]);
        bfrag k1 = ldfrag(&Ks[(mj * 16 + c) * 64 + ((quad + 4) ^ c7) * 8]);
        sacc[mj] = MFMA(k0, qf[qs][0], sacc[mj]);
        sacc[mj] = MFMA(k1, qf[qs][1], sacc[mj]);
      }
      // p = exp(s) (scores bounded ~|15|, safe in f32); pack 4 keys -> b64
      const int psrow = (qs * 16 + c) * 72;
#pragma unroll
      for (int mj = 0; mj < 4; mj++) {
        f32x4 p;
#pragma unroll
        for (int r = 0; r < 4; r++) p[r] = __expf(sacc[mj][r]);
        pack4_store(&psw[psrow + mj * 16 + quad * 4], p, 1.0f);
      }
    }

    // O^T += V^T @ P^T ; l += 1 @ P^T
    bfrag pf[2][2];
#pragma unroll
    for (int qs = 0; qs < 2; qs++) {
      pf[qs][0] = ldfrag(&psw[(qs * 16 + c) * 72 + quad * 8]);
      pf[qs][1] = ldfrag(&psw[(qs * 16 + c) * 72 + 32 + quad * 8]);
      lacc[qs] = MFMA(onesf, pf[qs][0], lacc[qs]);
      lacc[qs] = MFMA(onesf, pf[qs][1], lacc[qs]);
    }
#pragma unroll
    for (int dj = 0; dj < 4; dj++) {
      bfrag v0 = ldfrag(&Vs[(dj * 16 + c) * 64 + (quad ^ c7) * 8]);
      bfrag v1 = ldfrag(&Vs[(dj * 16 + c) * 64 + ((quad + 4) ^ c7) * 8]);
#pragma unroll
      for (int qs = 0; qs < 2; qs++) {
        oacc[qs][dj] = MFMA(v0, pf[qs][0], oacc[qs][dj]);
        oacc[qs][dj] = MFMA(v1, pf[qs][1], oacc[qs][dj]);
      }
    }
  }

  // O[q][h*64+d] = O^T / l ; pack 4 contiguous d -> 8B stores
#pragma unroll
  for (int qs = 0; qs < 2; qs++) {
    const float inv = 1.0f / lacc[qs][0];
    bf16* op =
        O + (size_t)(b * 1024 + qt * 128 + w * 32 + qs * 16 + c) * 1024 + h * 64 + quad * 4;
#pragma unroll
    for (int dj = 0; dj < 4; dj++) pack4_store(op + dj * 16, oacc[qs][dj], inv);
  }
}

// ---------------- launch ----------------

extern "C" void kernel_launch(void* const* d_in, const int* in_sizes, int n_in,
                              void* d_out, int out_size, void* d_ws, size_t ws_size,
                              hipStream_t stream) {
  const float* X  = (const float*)d_in[0];
  const float* rp = (const float*)d_in[1];
  const float* wq = (const float*)d_in[2];
  const float* bq = (const float*)d_in[3];
  const float* wk = (const float*)d_in[4];
  const float* bk = (const float*)d_in[5];
  const float* wv = (const float*)d_in[6];
  const float* bv = (const float*)d_in[7];
  const float* wo = (const float*)d_in[8];
  const float* bo = (const float*)d_in[9];
  float* out = (float*)d_out;

  char* ws = (char*)d_ws;
  const size_t MB = 1024 * 1024;
  bf16* Xb  = (bf16*)(ws + 0 * MB);    // 16 MB each
  bf16* Q   = (bf16*)(ws + 16 * MB);
  bf16* Kb  = (bf16*)(ws + 32 * MB);
  bf16* VT  = (bf16*)(ws + 48 * MB);   // [1024][8192]
  bf16* O   = (bf16*)(ws + 64 * MB);
  bf16* wqT = (bf16*)(ws + 80 * MB);   // 2 MB each
  bf16* wkT = (bf16*)(ws + 82 * MB);
  bf16* wvT = (bf16*)(ws + 84 * MB);
  bf16* woT = (bf16*)(ws + 86 * MB);
  float* ctab = (float*)(ws + 88 * MB);  // 128 KB
  float* stab = ctab + 1024 * 32;        // 128 KB

  k_tables<<<dim3(128), dim3(256), 0, stream>>>(rp, ctab, stab);
  k_convert_x<<<dim3(8192), dim3(256), 0, stream>>>(X, (unsigned short*)Xb);
  k_transpose_w<<<dim3(16, 16, 4), dim3(256), 0, stream>>>(
      wq, wk, wv, wo, (unsigned short*)wqT, (unsigned short*)wkT, (unsigned short*)wvT,
      (unsigned short*)woT);
  k_gemm_qkv<<<dim3(64, 8, 3), dim3(256), 0, stream>>>(Xb, wqT, wkT, wvT, bq, bk, bv, ctab,
                                                       stab, Q, Kb, VT);
  k_flash<<<dim3(8, 128), dim3(256), 0, stream>>>(Q, Kb, VT, O);
  k_gemm_o<<<dim3(64, 8, 1), dim3(256), 0, stream>>>(O, woT, bo, out);
}

// Round 5
// 243.513 us; speedup vs baseline: 1.4023x; 1.0048x over previous
//
#include <hip/hip_runtime.h>
#include <hip/hip_bf16.h>

typedef __hip_bfloat16 bf16;
typedef __attribute__((ext_vector_type(8))) short bfrag;   // 8 bf16 in 4 VGPRs
typedef __attribute__((ext_vector_type(4))) float f32x4;

#define MFMA(a, b, c) __builtin_amdgcn_mfma_f32_16x16x32_bf16((a), (b), (c), 0, 0, 0)

// async global->LDS, 16B per lane; LDS dest = wave-uniform base + lane*16
__device__ __forceinline__ void async16(const void* g, void* l) {
  __builtin_amdgcn_global_load_lds(
      (const __attribute__((address_space(1))) unsigned int*)g,
      (__attribute__((address_space(3))) unsigned int*)l, 16, 0, 0);
}

__device__ __forceinline__ bfrag ldfrag(const bf16* p) { return *(const bfrag*)p; }

__device__ __forceinline__ unsigned short f2b(float f) {
  return __hip_bfloat16_raw(__float2bfloat16(f)).x;
}
__device__ __forceinline__ float b2f(short u) {
  __hip_bfloat16_raw r; r.x = (unsigned short)u;
  return __bfloat162float(__hip_bfloat16(r));
}

// multiply a bf16 frag by 0.125 (exact: power of two)
__device__ __forceinline__ bfrag scale8(bfrag x) {
  bfrag y;
#pragma unroll
  for (int i = 0; i < 8; i++) y[i] = (short)f2b(b2f(x[i]) * 0.125f);
  return y;
}

__device__ __forceinline__ void pack4_store(bf16* p, f32x4 v, float s) {
  union { unsigned short h[4]; uint2 u; } pk;
#pragma unroll
  for (int i = 0; i < 4; i++) pk.h[i] = f2b(v[i] * s);
  *(uint2*)p = pk.u;
}

// ---------------- prep kernels ----------------

// X f32 -> bf16; blocks 0..127 also fill the rope cos/sin tables
__global__ void k_convert_x(const float* __restrict__ X, unsigned short* __restrict__ Xb,
                            const float* __restrict__ rp, float* __restrict__ ctab,
                            float* __restrict__ stab) {
  int i = blockIdx.x * 256 + threadIdx.x;
  if (blockIdx.x < 128) {  // 32768 table elems
    float f = rp[i];
    ctab[i] = cosf(f);
    stab[i] = sinf(f);
  }
  float4 v = *(const float4*)(X + (size_t)i * 4);
  union { unsigned short h[4]; uint2 u; } pk;
  pk.h[0] = f2b(v.x); pk.h[1] = f2b(v.y); pk.h[2] = f2b(v.z); pk.h[3] = f2b(v.w);
  *(uint2*)(Xb + (size_t)i * 4) = pk.u;
}

// w f32 (K=1024 x N=1024) row-major -> wT bf16 (N x K) row-major. LDS-tiled 64x64.
__global__ void k_transpose_w(const float* __restrict__ wq, const float* __restrict__ wk,
                              const float* __restrict__ wv, const float* __restrict__ wo,
                              unsigned short* __restrict__ tq, unsigned short* __restrict__ tk,
                              unsigned short* __restrict__ tv, unsigned short* __restrict__ to) {
  __shared__ unsigned short T[64][72];
  const int z = blockIdx.z;
  const float* src = (z == 0) ? wq : (z == 1) ? wk : (z == 2) ? wv : wo;
  unsigned short* dst = (z == 0) ? tq : (z == 1) ? tk : (z == 2) ? tv : to;
  const int k0 = blockIdx.y * 64, n0 = blockIdx.x * 64;
  const int t = threadIdx.x;
  const int kr = t >> 4;          // 0..15
  const int nc = (t & 15) * 4;    // 0..60
#pragma unroll
  for (int g = 0; g < 4; g++) {   // coalesced f32x4 reads
    float4 v = *(const float4*)(src + (size_t)(k0 + g * 16 + kr) * 1024 + n0 + nc);
    const int kk = g * 16 + kr;
    T[nc + 0][kk] = f2b(v.x);
    T[nc + 1][kk] = f2b(v.y);
    T[nc + 2][kk] = f2b(v.z);
    T[nc + 3][kk] = f2b(v.w);
  }
  __syncthreads();
  const int nr = t >> 2;          // 0..63
  const int kc = (t & 3) * 16;    // 16 bf16 = 2 x uint4 per thread
  unsigned short* dp = dst + (size_t)(n0 + nr) * 1024 + k0 + kc;
  *(uint4*)(dp + 0) = *(const uint4*)(&T[nr][kc + 0]);
  *(uint4*)(dp + 8) = *(const uint4*)(&T[nr][kc + 8]);
}

// ---------------- GEMM cores: BK=64, XOR-swizzled LDS --------------------------
// LDS layout: row stride 64 bf16 (128 B); 16B chunk p of row r holds global
// chunk p ^ (r & 7)  -> frag reads spread across all 32 banks (2-way = free).
// BT is pre-offset to its first row (n0 only addresses C/bias).

// 128x128 tile, fused-RoPE bf16 output (Q/K GEMM)
__device__ __forceinline__ void gemm128_rope(bf16* As, bf16* Bs, int m0, int n0,
                                             const bf16* __restrict__ A,
                                             const bf16* __restrict__ BT,
                                             const float* __restrict__ bias,
                                             bf16* __restrict__ C,
                                             const float* __restrict__ ctab,
                                             const float* __restrict__ stab) {
  const int tid = threadIdx.x;
  const int w = tid >> 6, l = tid & 63;
  const int wm = (w >> 1) << 6, wn = (w & 1) << 6;  // 2x2 waves over 128x128
  const int c = l & 15, quad = l >> 4;
  const int c7 = c & 7;

  f32x4 acc[4][4] = {};

  const int rl = l >> 3, ch = l & 7;
  const int sc = (ch ^ rl) * 8;
  const bf16* gA = A + (size_t)(m0 + w * 32 + rl) * 1024 + sc;
  const bf16* gB = BT + (size_t)(w * 32 + rl) * 1024 + sc;
  char* lA = (char*)As + w * 32 * 128;
  char* lB = (char*)Bs + w * 32 * 128;

  for (int k0 = 0; k0 < 1024; k0 += 64) {
    __syncthreads();
#pragma unroll
    for (int g = 0; g < 4; g++) {
      async16(gA + (size_t)g * 8 * 1024 + k0, lA + g * 1024);
      async16(gB + (size_t)g * 8 * 1024 + k0, lB + g * 1024);
    }
    __syncthreads();
#pragma unroll
    for (int ks = 0; ks < 2; ks++) {
      bfrag a[4], b[4];
#pragma unroll
      for (int i = 0; i < 4; i++)
        a[i] = ldfrag(&As[(wm + i * 16 + c) * 64 + (((ks * 4 + quad) ^ c7) * 8)]);
#pragma unroll
      for (int j = 0; j < 4; j++)
        b[j] = ldfrag(&Bs[(wn + j * 16 + c) * 64 + (((ks * 4 + quad) ^ c7) * 8)]);
#pragma unroll
      for (int i = 0; i < 4; i++)
#pragma unroll
        for (int j = 0; j < 4; j++) acc[i][j] = MFMA(a[i], b[j], acc[i][j]);
    }
  }

  // epilogue with fused RoPE: wave spans 64 aligned cols (one head);
  // d = j*16+c (0..31) pairs with tile j+2 (d+32), same lane.
#pragma unroll
  for (int i = 0; i < 4; i++) {
    const int mb = m0 + wm + i * 16 + quad * 4;
#pragma unroll
    for (int j = 0; j < 2; j++) {
      const int n1 = n0 + wn + j * 16 + c;
      const int n2 = n1 + 32;
      const int dl = j * 16 + c;  // 0..31
      const float b1 = bias[n1];
      const float b2 = bias[n2];
#pragma unroll
      for (int r = 0; r < 4; r++) {
        const int m = mb + r;
        const int s = m & 1023;
        const float cs = ctab[s * 32 + dl];
        const float sn = stab[s * 32 + dl];
        const float t1 = acc[i][j][r] + b1;
        const float t2 = acc[i][j + 2][r] + b2;
        C[(size_t)m * 1024 + n1] = __float2bfloat16(t1 * cs - t2 * sn);  // d < 32
        C[(size_t)m * 1024 + n2] = __float2bfloat16(t2 * cs + t1 * sn);  // d >= 32
      }
    }
  }
}

// 64x128 tile (for 1024-block grids on the smaller GEMMs)
template <bool F32OUT, bool BIAS_ROW, int CSTRIDE>
__device__ __forceinline__ void gemm64_core(bf16* As, bf16* Bs, int m0, int n0,
                                            const bf16* __restrict__ A,
                                            const bf16* __restrict__ BT,
                                            const float* __restrict__ bias,
                                            bf16* __restrict__ C, float* __restrict__ Cf) {
  const int tid = threadIdx.x;
  const int w = tid >> 6, l = tid & 63;
  const int wm = (w >> 1) << 5, wn = (w & 1) << 6;  // 2x2 waves over 64x128
  const int c = l & 15, quad = l >> 4;
  const int c7 = c & 7;

  f32x4 acc[2][4] = {};

  const int rl = l >> 3, ch = l & 7;
  const int sc = (ch ^ rl) * 8;
  const bf16* gA = A + (size_t)(m0 + w * 16 + rl) * 1024 + sc;
  const bf16* gB = BT + (size_t)(w * 32 + rl) * 1024 + sc;
  char* lA = (char*)As + w * 16 * 128;
  char* lB = (char*)Bs + w * 32 * 128;

  for (int k0 = 0; k0 < 1024; k0 += 64) {
    __syncthreads();
#pragma unroll
    for (int g = 0; g < 2; g++) async16(gA + (size_t)g * 8 * 1024 + k0, lA + g * 1024);
#pragma unroll
    for (int g = 0; g < 4; g++) async16(gB + (size_t)g * 8 * 1024 + k0, lB + g * 1024);
    __syncthreads();
#pragma unroll
    for (int ks = 0; ks < 2; ks++) {
      bfrag a[2], b[4];
#pragma unroll
      for (int i = 0; i < 2; i++)
        a[i] = ldfrag(&As[(wm + i * 16 + c) * 64 + (((ks * 4 + quad) ^ c7) * 8)]);
#pragma unroll
      for (int j = 0; j < 4; j++)
        b[j] = ldfrag(&Bs[(wn + j * 16 + c) * 64 + (((ks * 4 + quad) ^ c7) * 8)]);
#pragma unroll
      for (int i = 0; i < 2; i++)
#pragma unroll
        for (int j = 0; j < 4; j++) acc[i][j] = MFMA(a[i], b[j], acc[i][j]);
    }
  }

#pragma unroll
  for (int i = 0; i < 2; i++) {
    const int mb = m0 + wm + i * 16 + quad * 4;
    float brow[4];
    if (BIAS_ROW) {
#pragma unroll
      for (int r = 0; r < 4; r++) brow[r] = bias[mb + r];
    }
#pragma unroll
    for (int j = 0; j < 4; j++) {
      const int n = n0 + wn + j * 16 + c;
      const float bcol = BIAS_ROW ? 0.0f : bias[n];
#pragma unroll
      for (int r = 0; r < 4; r++) {
        const float val = acc[i][j][r] + (BIAS_ROW ? brow[r] : bcol);
        if (F32OUT)
          Cf[(size_t)(mb + r) * CSTRIDE + n] = val;
        else
          C[(size_t)(mb + r) * CSTRIDE + n] = __float2bfloat16(val);
      }
    }
  }
}

// Q+K fused: BT = wqkT (2048 x 1024, wqT then wkT contiguous). grid (64,16).
__global__ __launch_bounds__(256) void k_gemm_qk(
    const bf16* __restrict__ X, const bf16* __restrict__ wqkT, const float* __restrict__ bq,
    const float* __restrict__ bk, const float* __restrict__ ctab,
    const float* __restrict__ stab, bf16* __restrict__ Q, bf16* __restrict__ Kb) {
  __shared__ __align__(16) bf16 As[128 * 64];
  __shared__ __align__(16) bf16 Bs[128 * 64];
  const int nblk = blockIdx.y;  // 0..15
  const bf16* BT = wqkT + (size_t)nblk * 128 * 1024;
  const bool isK = nblk >= 8;
  gemm128_rope(As, Bs, blockIdx.x * 128, (nblk & 7) * 128, X, BT, isK ? bk : bq,
               isK ? Kb : Q, ctab, stab);
}

// VT = Wv^T @ X^T (1024 x 8192), bias by row. grid (64 s-blocks, 16 v-blocks).
__global__ __launch_bounds__(256) void k_gemm_vt(const bf16* __restrict__ wvT,
                                                 const bf16* __restrict__ X,
                                                 const float* __restrict__ bv,
                                                 bf16* __restrict__ VT) {
  __shared__ __align__(16) bf16 As[64 * 64];
  __shared__ __align__(16) bf16 Bs[128 * 64];
  gemm64_core<false, true, 8192>(As, Bs, blockIdx.y * 64, blockIdx.x * 128, wvT,
                                 X + (size_t)blockIdx.x * 128 * 1024, bv, VT, nullptr);
}

// out = O @ Wo^T + bo, f32 output. grid (128 m-blocks, 8 n-blocks).
__global__ __launch_bounds__(256) void k_gemm_o(const bf16* __restrict__ A,
                                                const bf16* __restrict__ woT,
                                                const float* __restrict__ bias,
                                                float* __restrict__ Cf) {
  __shared__ __align__(16) bf16 As[64 * 64];
  __shared__ __align__(16) bf16 Bs[128 * 64];
  gemm64_core<true, false, 1024>(As, Bs, blockIdx.x * 64, blockIdx.y * 128, A,
                                 woT + (size_t)blockIdx.y * 128 * 1024, bias, nullptr, Cf);
}

// ---------------- flash attention (no-max online softmax, S^T/O^T form) -------
// grid: (qt 0..7, bh 0..127). block = 256 = 4 waves; wave w owns 32 q rows.
// VT: [1024 vcols][8192 s]  (vcol = h*64+d, s = b*1024+s')

__global__ __launch_bounds__(256, 4) void k_flash(const bf16* __restrict__ Q,
                                                  const bf16* __restrict__ K,
                                                  const bf16* __restrict__ VT,
                                                  bf16* __restrict__ O) {
  __shared__ __align__(16) bf16 Ks[64 * 64];     // [key][d], chunk-swizzled
  __shared__ __align__(16) bf16 Vs[64 * 64];     // [d][key], chunk-swizzled
  __shared__ __align__(16) bf16 Ps[4][32 * 72];  // per-wave P [qrow][key], stride 72
  const int qt = blockIdx.x, bh = blockIdx.y;
  const int b = bh >> 4, h = bh & 15;
  const int tid = threadIdx.x, w = tid >> 6, l = tid & 63;
  const int c = l & 15, quad = l >> 4;
  const int c7 = c & 7;

  // Q B-frags (n = q), pre-scaled by 1/8 (exact)
  bfrag qf[2][2];
#pragma unroll
  for (int qs = 0; qs < 2; qs++) {
    const bf16* qp =
        Q + (size_t)(b * 1024 + qt * 128 + w * 32 + qs * 16 + c) * 1024 + h * 64 + quad * 8;
    qf[qs][0] = scale8(ldfrag(qp));
    qf[qs][1] = scale8(ldfrag(qp + 32));
  }

  bfrag onesf;
#pragma unroll
  for (int i = 0; i < 8; i++) onesf[i] = (short)0x3F80;  // 1.0 bf16

  f32x4 oacc[2][4] = {};  // O^T: [qs][dj], row d = dj*16+quad*4+r, col q
  f32x4 lacc[2] = {};     // row sums l[q]

  // staging: wave w covers rows w*16+sr and +8; global chunk xor-swizzled by row&7
  const int sr = l >> 3, scc = l & 7;
  const int swz = (scc ^ sr) * 8;
  const bf16* gK0 = K + (size_t)(b * 1024 + w * 16 + sr) * 1024 + h * 64 + swz;
  const bf16* gV0 = VT + (size_t)(h * 64 + w * 16 + sr) * 8192 + b * 1024 + swz;
  char* lK = (char*)Ks + w * 2048;
  char* lV = (char*)Vs + w * 2048;
  bf16* psw = Ps[w];

  for (int kt = 0; kt < 16; kt++) {
    __syncthreads();
    async16(gK0 + (size_t)(kt * 64) * 1024, lK);
    async16(gK0 + (size_t)(kt * 64 + 8) * 1024, lK + 1024);
    async16(gV0 + kt * 64, lV);
    async16(gV0 + 8 * 8192 + kt * 64, lV + 1024);
    __syncthreads();

    // S^T = K @ Q^T : A = K (m = key), B = Q^T. C row = key, col = q.
#pragma unroll
    for (int qs = 0; qs < 2; qs++) {
      f32x4 sacc[4] = {};
#pragma unroll
      for (int mj = 0; mj < 4; mj++) {
        bfrag k0 = ldfrag(&Ks[(mj * 16 + c) * 64 + (quad ^ c7) * 8]);
        bfrag k1 = ldfrag(&Ks[(mj * 16 + c) * 64 + ((quad + 4) ^ c7) * 8]);
        sacc[mj] = MFMA(k0, qf[qs][0], sacc[mj]);
        sacc[mj] = MFMA(k1, qf[qs][1], sacc[mj]);
      }
      // p = exp(s) (scores bounded ~|15|, safe in f32); pack 4 keys -> b64
      const int psrow = (qs * 16 + c) * 72;
#pragma unroll
      for (int mj = 0; mj < 4; mj++) {
        f32x4 p;
#pragma unroll
        for (int r = 0; r < 4; r++) p[r] = __expf(sacc[mj][r]);
        pack4_store(&psw[psrow + mj * 16 + quad * 4], p, 1.0f);
      }
    }

    // O^T += V^T @ P^T ; l += 1 @ P^T
    bfrag pf[2][2];
#pragma unroll
    for (int qs = 0; qs < 2; qs++) {
      pf[qs][0] = ldfrag(&psw[(qs * 16 + c) * 72 + quad * 8]);
      pf[qs][1] = ldfrag(&psw[(qs * 16 + c) * 72 + 32 + quad * 8]);
      lacc[qs] = MFMA(onesf, pf[qs][0], lacc[qs]);
      lacc[qs] = MFMA(onesf, pf[qs][1], lacc[qs]);
    }
#pragma unroll
    for (int dj = 0; dj < 4; dj++) {
      bfrag v0 = ldfrag(&Vs[(dj * 16 + c) * 64 + (quad ^ c7) * 8]);
      bfrag v1 = ldfrag(&Vs[(dj * 16 + c) * 64 + ((quad + 4) ^ c7) * 8]);
#pragma unroll
      for (int qs = 0; qs < 2; qs++) {
        oacc[qs][dj] = MFMA(v0, pf[qs][0], oacc[qs][dj]);
        oacc[qs][dj] = MFMA(v1, pf[qs][1], oacc[qs][dj]);
      }
    }
  }

  // O[q][h*64+d] = O^T / l ; pack 4 contiguous d -> 8B stores
#pragma unroll
  for (int qs = 0; qs < 2; qs++) {
    const float inv = 1.0f / lacc[qs][0];
    bf16* op =
        O + (size_t)(b * 1024 + qt * 128 + w * 32 + qs * 16 + c) * 1024 + h * 64 + quad * 4;
#pragma unroll
    for (int dj = 0; dj < 4; dj++) pack4_store(op + dj * 16, oacc[qs][dj], inv);
  }
}

// ---------------- launch ----------------

extern "C" void kernel_launch(void* const* d_in, const int* in_sizes, int n_in,
                              void* d_out, int out_size, void* d_ws, size_t ws_size,
                              hipStream_t stream) {
  const float* X  = (const float*)d_in[0];
  const float* rp = (const float*)d_in[1];
  const float* wq = (const float*)d_in[2];
  const float* bq = (const float*)d_in[3];
  const float* wk = (const float*)d_in[4];
  const float* bk = (const float*)d_in[5];
  const float* wv = (const float*)d_in[6];
  const float* bv = (const float*)d_in[7];
  const float* wo = (const float*)d_in[8];
  const float* bo = (const float*)d_in[9];
  float* out = (float*)d_out;

  char* ws = (char*)d_ws;
  const size_t MB = 1024 * 1024;
  bf16* Xb  = (bf16*)(ws + 0 * MB);    // 16 MB each
  bf16* Q   = (bf16*)(ws + 16 * MB);
  bf16* Kb  = (bf16*)(ws + 32 * MB);
  bf16* VT  = (bf16*)(ws + 48 * MB);   // [1024][8192]
  bf16* O   = (bf16*)(ws + 64 * MB);
  bf16* wqT = (bf16*)(ws + 80 * MB);   // 2 MB each; wqT+wkT contiguous = wqkT
  bf16* wkT = (bf16*)(ws + 82 * MB);
  bf16* wvT = (bf16*)(ws + 84 * MB);
  bf16* woT = (bf16*)(ws + 86 * MB);
  float* ctab = (float*)(ws + 88 * MB);  // 128 KB
  float* stab = ctab + 1024 * 32;        // 128 KB

  k_convert_x<<<dim3(8192), dim3(256), 0, stream>>>(X, (unsigned short*)Xb, rp, ctab, stab);
  k_transpose_w<<<dim3(16, 16, 4), dim3(256), 0, stream>>>(
      wq, wk, wv, wo, (unsigned short*)wqT, (unsigned short*)wkT, (unsigned short*)wvT,
      (unsigned short*)woT);
  k_gemm_qk<<<dim3(64, 16), dim3(256), 0, stream>>>(Xb, wqT, bq, bk, ctab, stab, Q, Kb);
  k_gemm_vt<<<dim3(64, 16), dim3(256), 0, stream>>>(wvT, Xb, bv, VT);
  k_flash<<<dim3(8, 128), dim3(256), 0, stream>>>(Q, Kb, VT, O);
  k_gemm_o<<<dim3(128, 8), dim3(256), 0, stream>>>(O, woT, bo, out);
}

// Round 6
// 237.962 us; speedup vs baseline: 1.4350x; 1.0233x over previous
//
#include <hip/hip_runtime.h>
#include <hip/hip_bf16.h>

typedef __hip_bfloat16 bf16;
typedef __attribute__((ext_vector_type(8))) short bfrag;   // 8 bf16 in 4 VGPRs
typedef __attribute__((ext_vector_type(4))) float f32x4;

#define MFMA(a, b, c) __builtin_amdgcn_mfma_f32_16x16x32_bf16((a), (b), (c), 0, 0, 0)

// async global->LDS, 16B per lane; LDS dest = wave-uniform base + lane*16
__device__ __forceinline__ void async16(const void* g, void* l) {
  __builtin_amdgcn_global_load_lds(
      (const __attribute__((address_space(1))) unsigned int*)g,
      (__attribute__((address_space(3))) unsigned int*)l, 16, 0, 0);
}

__device__ __forceinline__ bfrag ldfrag(const bf16* p) { return *(const bfrag*)p; }

__device__ __forceinline__ unsigned short f2b(float f) {
  return __hip_bfloat16_raw(__float2bfloat16(f)).x;
}
__device__ __forceinline__ float b2f(short u) {
  __hip_bfloat16_raw r; r.x = (unsigned short)u;
  return __bfloat162float(__hip_bfloat16(r));
}

// multiply a bf16 frag by 0.125 (exact: power of two)
__device__ __forceinline__ bfrag scale8(bfrag x) {
  bfrag y;
#pragma unroll
  for (int i = 0; i < 8; i++) y[i] = (short)f2b(b2f(x[i]) * 0.125f);
  return y;
}

__device__ __forceinline__ void pack4_store(bf16* p, f32x4 v, float s) {
  union { unsigned short h[4]; uint2 u; } pk;
#pragma unroll
  for (int i = 0; i < 4; i++) pk.h[i] = f2b(v[i] * s);
  *(uint2*)p = pk.u;
}

// ---------------- prep kernels ----------------

// X f32 -> bf16; blocks 0..127 also fill the rope cos/sin tables
__global__ void k_convert_x(const float* __restrict__ X, unsigned short* __restrict__ Xb,
                            const float* __restrict__ rp, float* __restrict__ ctab,
                            float* __restrict__ stab) {
  int i = blockIdx.x * 256 + threadIdx.x;
  if (blockIdx.x < 128) {  // 32768 table elems
    float f = rp[i];
    ctab[i] = cosf(f);
    stab[i] = sinf(f);
  }
  float4 v = *(const float4*)(X + (size_t)i * 4);
  union { unsigned short h[4]; uint2 u; } pk;
  pk.h[0] = f2b(v.x); pk.h[1] = f2b(v.y); pk.h[2] = f2b(v.z); pk.h[3] = f2b(v.w);
  *(uint2*)(Xb + (size_t)i * 4) = pk.u;
}

// w f32 (K=1024 x N=1024) row-major -> wT bf16 (N x K) row-major. LDS-tiled 64x64.
__global__ void k_transpose_w(const float* __restrict__ wq, const float* __restrict__ wk,
                              const float* __restrict__ wv, const float* __restrict__ wo,
                              unsigned short* __restrict__ tq, unsigned short* __restrict__ tk,
                              unsigned short* __restrict__ tv, unsigned short* __restrict__ to) {
  __shared__ unsigned short T[64][72];
  const int z = blockIdx.z;
  const float* src = (z == 0) ? wq : (z == 1) ? wk : (z == 2) ? wv : wo;
  unsigned short* dst = (z == 0) ? tq : (z == 1) ? tk : (z == 2) ? tv : to;
  const int k0 = blockIdx.y * 64, n0 = blockIdx.x * 64;
  const int t = threadIdx.x;
  const int kr = t >> 4;          // 0..15
  const int nc = (t & 15) * 4;    // 0..60
#pragma unroll
  for (int g = 0; g < 4; g++) {   // coalesced f32x4 reads
    float4 v = *(const float4*)(src + (size_t)(k0 + g * 16 + kr) * 1024 + n0 + nc);
    const int kk = g * 16 + kr;
    T[nc + 0][kk] = f2b(v.x);
    T[nc + 1][kk] = f2b(v.y);
    T[nc + 2][kk] = f2b(v.z);
    T[nc + 3][kk] = f2b(v.w);
  }
  __syncthreads();
  const int nr = t >> 2;          // 0..63
  const int kc = (t & 3) * 16;    // 16 bf16 = 2 x uint4 per thread
  unsigned short* dp = dst + (size_t)(n0 + nr) * 1024 + k0 + kc;
  *(uint4*)(dp + 0) = *(const uint4*)(&T[nr][kc + 0]);
  *(uint4*)(dp + 8) = *(const uint4*)(&T[nr][kc + 8]);
}

// ---------------- GEMM cores: BK=64, XOR-swizzled LDS --------------------------
// LDS layout: row stride 64 bf16 (128 B); 16B chunk p of row r holds global
// chunk p ^ (r & 7)  -> frag reads spread across all 32 banks (2-way = free).
// BT is pre-offset to its first row (n0 only addresses C/bias).

// 128x128 tile, fused-RoPE bf16 output (Q/K GEMM)
__device__ __forceinline__ void gemm128_rope(bf16* As, bf16* Bs, int m0, int n0,
                                             const bf16* __restrict__ A,
                                             const bf16* __restrict__ BT,
                                             const float* __restrict__ bias,
                                             bf16* __restrict__ C,
                                             const float* __restrict__ ctab,
                                             const float* __restrict__ stab) {
  const int tid = threadIdx.x;
  const int w = tid >> 6, l = tid & 63;
  const int wm = (w >> 1) << 6, wn = (w & 1) << 6;  // 2x2 waves over 128x128
  const int c = l & 15, quad = l >> 4;
  const int c7 = c & 7;

  f32x4 acc[4][4] = {};

  const int rl = l >> 3, ch = l & 7;
  const int sc = (ch ^ rl) * 8;
  const bf16* gA = A + (size_t)(m0 + w * 32 + rl) * 1024 + sc;
  const bf16* gB = BT + (size_t)(w * 32 + rl) * 1024 + sc;
  char* lA = (char*)As + w * 32 * 128;
  char* lB = (char*)Bs + w * 32 * 128;

  for (int k0 = 0; k0 < 1024; k0 += 64) {
    __syncthreads();
#pragma unroll
    for (int g = 0; g < 4; g++) {
      async16(gA + (size_t)g * 8 * 1024 + k0, lA + g * 1024);
      async16(gB + (size_t)g * 8 * 1024 + k0, lB + g * 1024);
    }
    __syncthreads();
#pragma unroll
    for (int ks = 0; ks < 2; ks++) {
      bfrag a[4], b[4];
#pragma unroll
      for (int i = 0; i < 4; i++)
        a[i] = ldfrag(&As[(wm + i * 16 + c) * 64 + (((ks * 4 + quad) ^ c7) * 8)]);
#pragma unroll
      for (int j = 0; j < 4; j++)
        b[j] = ldfrag(&Bs[(wn + j * 16 + c) * 64 + (((ks * 4 + quad) ^ c7) * 8)]);
#pragma unroll
      for (int i = 0; i < 4; i++)
#pragma unroll
        for (int j = 0; j < 4; j++) acc[i][j] = MFMA(a[i], b[j], acc[i][j]);
    }
  }

  // epilogue with fused RoPE: wave spans 64 aligned cols (one head);
  // d = j*16+c (0..31) pairs with tile j+2 (d+32), same lane.
#pragma unroll
  for (int i = 0; i < 4; i++) {
    const int mb = m0 + wm + i * 16 + quad * 4;
#pragma unroll
    for (int j = 0; j < 2; j++) {
      const int n1 = n0 + wn + j * 16 + c;
      const int n2 = n1 + 32;
      const int dl = j * 16 + c;  // 0..31
      const float b1 = bias[n1];
      const float b2 = bias[n2];
#pragma unroll
      for (int r = 0; r < 4; r++) {
        const int m = mb + r;
        const int s = m & 1023;
        const float cs = ctab[s * 32 + dl];
        const float sn = stab[s * 32 + dl];
        const float t1 = acc[i][j][r] + b1;
        const float t2 = acc[i][j + 2][r] + b2;
        C[(size_t)m * 1024 + n1] = __float2bfloat16(t1 * cs - t2 * sn);  // d < 32
        C[(size_t)m * 1024 + n2] = __float2bfloat16(t2 * cs + t1 * sn);  // d >= 32
      }
    }
  }
}

// 64x128 tile (for 1024-block grids on the smaller GEMMs)
template <bool F32OUT, bool BIAS_ROW, int CSTRIDE>
__device__ __forceinline__ void gemm64_core(bf16* As, bf16* Bs, int m0, int n0,
                                            const bf16* __restrict__ A,
                                            const bf16* __restrict__ BT,
                                            const float* __restrict__ bias,
                                            bf16* __restrict__ C, float* __restrict__ Cf) {
  const int tid = threadIdx.x;
  const int w = tid >> 6, l = tid & 63;
  const int wm = (w >> 1) << 5, wn = (w & 1) << 6;  // 2x2 waves over 64x128
  const int c = l & 15, quad = l >> 4;
  const int c7 = c & 7;

  f32x4 acc[2][4] = {};

  const int rl = l >> 3, ch = l & 7;
  const int sc = (ch ^ rl) * 8;
  const bf16* gA = A + (size_t)(m0 + w * 16 + rl) * 1024 + sc;
  const bf16* gB = BT + (size_t)(w * 32 + rl) * 1024 + sc;
  char* lA = (char*)As + w * 16 * 128;
  char* lB = (char*)Bs + w * 32 * 128;

  for (int k0 = 0; k0 < 1024; k0 += 64) {
    __syncthreads();
#pragma unroll
    for (int g = 0; g < 2; g++) async16(gA + (size_t)g * 8 * 1024 + k0, lA + g * 1024);
#pragma unroll
    for (int g = 0; g < 4; g++) async16(gB + (size_t)g * 8 * 1024 + k0, lB + g * 1024);
    __syncthreads();
#pragma unroll
    for (int ks = 0; ks < 2; ks++) {
      bfrag a[2], b[4];
#pragma unroll
      for (int i = 0; i < 2; i++)
        a[i] = ldfrag(&As[(wm + i * 16 + c) * 64 + (((ks * 4 + quad) ^ c7) * 8)]);
#pragma unroll
      for (int j = 0; j < 4; j++)
        b[j] = ldfrag(&Bs[(wn + j * 16 + c) * 64 + (((ks * 4 + quad) ^ c7) * 8)]);
#pragma unroll
      for (int i = 0; i < 2; i++)
#pragma unroll
        for (int j = 0; j < 4; j++) acc[i][j] = MFMA(a[i], b[j], acc[i][j]);
    }
  }

#pragma unroll
  for (int i = 0; i < 2; i++) {
    const int mb = m0 + wm + i * 16 + quad * 4;
    float brow[4];
    if (BIAS_ROW) {
#pragma unroll
      for (int r = 0; r < 4; r++) brow[r] = bias[mb + r];
    }
#pragma unroll
    for (int j = 0; j < 4; j++) {
      const int n = n0 + wn + j * 16 + c;
      const float bcol = BIAS_ROW ? 0.0f : bias[n];
#pragma unroll
      for (int r = 0; r < 4; r++) {
        const float val = acc[i][j][r] + (BIAS_ROW ? brow[r] : bcol);
        if (F32OUT)
          Cf[(size_t)(mb + r) * CSTRIDE + n] = val;
        else
          C[(size_t)(mb + r) * CSTRIDE + n] = __float2bfloat16(val);
      }
    }
  }
}

// Q+K fused: BT = wqkT (2048 x 1024, wqT then wkT contiguous). grid (64,16).
__global__ __launch_bounds__(256) void k_gemm_qk(
    const bf16* __restrict__ X, const bf16* __restrict__ wqkT, const float* __restrict__ bq,
    const float* __restrict__ bk, const float* __restrict__ ctab,
    const float* __restrict__ stab, bf16* __restrict__ Q, bf16* __restrict__ Kb) {
  __shared__ __align__(16) bf16 As[128 * 64];
  __shared__ __align__(16) bf16 Bs[128 * 64];
  const int nblk = blockIdx.y;  // 0..15
  const bf16* BT = wqkT + (size_t)nblk * 128 * 1024;
  const bool isK = nblk >= 8;
  gemm128_rope(As, Bs, blockIdx.x * 128, (nblk & 7) * 128, X, BT, isK ? bk : bq,
               isK ? Kb : Q, ctab, stab);
}

// VT = Wv^T @ X^T (1024 x 8192), bias by row. grid (64 s-blocks, 16 v-blocks).
__global__ __launch_bounds__(256) void k_gemm_vt(const bf16* __restrict__ wvT,
                                                 const bf16* __restrict__ X,
                                                 const float* __restrict__ bv,
                                                 bf16* __restrict__ VT) {
  __shared__ __align__(16) bf16 As[64 * 64];
  __shared__ __align__(16) bf16 Bs[128 * 64];
  gemm64_core<false, true, 8192>(As, Bs, blockIdx.y * 64, blockIdx.x * 128, wvT,
                                 X + (size_t)blockIdx.x * 128 * 1024, bv, VT, nullptr);
}

// out = O @ Wo^T + bo, f32 output. grid (128 m-blocks, 8 n-blocks).
__global__ __launch_bounds__(256) void k_gemm_o(const bf16* __restrict__ A,
                                                const bf16* __restrict__ woT,
                                                const float* __restrict__ bias,
                                                float* __restrict__ Cf) {
  __shared__ __align__(16) bf16 As[64 * 64];
  __shared__ __align__(16) bf16 Bs[128 * 64];
  gemm64_core<true, false, 1024>(As, Bs, blockIdx.x * 64, blockIdx.y * 128, A,
                                 woT + (size_t)blockIdx.y * 128 * 1024, bias, nullptr, Cf);
}

// ---------------- flash attention (no-max online softmax, S^T/O^T form) -------
// grid: (bh 0..127, qt 0..7) -- bh on x so all 8 qt-blocks of one bh get linear
// ids == bh (mod 8) -> same XCD -> K/V re-reads hit that XCD's L2 instead of HBM.
// block = 256 = 4 waves; wave w owns 32 q rows.
// VT: [1024 vcols][8192 s]  (vcol = h*64+d, s = b*1024+s')

__global__ __launch_bounds__(256, 4) void k_flash(const bf16* __restrict__ Q,
                                                  const bf16* __restrict__ K,
                                                  const bf16* __restrict__ VT,
                                                  bf16* __restrict__ O) {
  __shared__ __align__(16) bf16 Ks[64 * 64];     // [key][d], chunk-swizzled
  __shared__ __align__(16) bf16 Vs[64 * 64];     // [d][key], chunk-swizzled
  __shared__ __align__(16) bf16 Ps[4][32 * 72];  // per-wave P [qrow][key], stride 72
  const int qt = blockIdx.y, bh = blockIdx.x;
  const int b = bh >> 4, h = bh & 15;
  const int tid = threadIdx.x, w = tid >> 6, l = tid & 63;
  const int c = l & 15, quad = l >> 4;
  const int c7 = c & 7;

  // Q B-frags (n = q), pre-scaled by 1/8 (exact)
  bfrag qf[2][2];
#pragma unroll
  for (int qs = 0; qs < 2; qs++) {
    const bf16* qp =
        Q + (size_t)(b * 1024 + qt * 128 + w * 32 + qs * 16 + c) * 1024 + h * 64 + quad * 8;
    qf[qs][0] = scale8(ldfrag(qp));
    qf[qs][1] = scale8(ldfrag(qp + 32));
  }

  bfrag onesf;
#pragma unroll
  for (int i = 0; i < 8; i++) onesf[i] = (short)0x3F80;  // 1.0 bf16

  f32x4 oacc[2][4] = {};  // O^T: [qs][dj], row d = dj*16+quad*4+r, col q
  f32x4 lacc[2] = {};     // row sums l[q]

  // staging: wave w covers rows w*16+sr and +8; global chunk xor-swizzled by row&7
  const int sr = l >> 3, scc = l & 7;
  const int swz = (scc ^ sr) * 8;
  const bf16* gK0 = K + (size_t)(b * 1024 + w * 16 + sr) * 1024 + h * 64 + swz;
  const bf16* gV0 = VT + (size_t)(h * 64 + w * 16 + sr) * 8192 + b * 1024 + swz;
  char* lK = (char*)Ks + w * 2048;
  char* lV = (char*)Vs + w * 2048;
  bf16* psw = Ps[w];

  for (int kt = 0; kt < 16; kt++) {
    __syncthreads();
    async16(gK0 + (size_t)(kt * 64) * 1024, lK);
    async16(gK0 + (size_t)(kt * 64 + 8) * 1024, lK + 1024);
    async16(gV0 + kt * 64, lV);
    async16(gV0 + 8 * 8192 + kt * 64, lV + 1024);
    __syncthreads();

    // S^T = K @ Q^T : A = K (m = key), B = Q^T. C row = key, col = q.
#pragma unroll
    for (int qs = 0; qs < 2; qs++) {
      f32x4 sacc[4] = {};
#pragma unroll
      for (int mj = 0; mj < 4; mj++) {
        bfrag k0 = ldfrag(&Ks[(mj * 16 + c) * 64 + (quad ^ c7) * 8]);
        bfrag k1 = ldfrag(&Ks[(mj * 16 + c) * 64 + ((quad + 4) ^ c7) * 8]);
        sacc[mj] = MFMA(k0, qf[qs][0], sacc[mj]);
        sacc[mj] = MFMA(k1, qf[qs][1], sacc[mj]);
      }
      // p = exp(s) (scores bounded ~|15|, safe in f32); pack 4 keys -> b64
      const int psrow = (qs * 16 + c) * 72;
#pragma unroll
      for (int mj = 0; mj < 4; mj++) {
        f32x4 p;
#pragma unroll
        for (int r = 0; r < 4; r++) p[r] = __expf(sacc[mj][r]);
        pack4_store(&psw[psrow + mj * 16 + quad * 4], p, 1.0f);
      }
    }

    // O^T += V^T @ P^T ; l += 1 @ P^T
    bfrag pf[2][2];
#pragma unroll
    for (int qs = 0; qs < 2; qs++) {
      pf[qs][0] = ldfrag(&psw[(qs * 16 + c) * 72 + quad * 8]);
      pf[qs][1] = ldfrag(&psw[(qs * 16 + c) * 72 + 32 + quad * 8]);
      lacc[qs] = MFMA(onesf, pf[qs][0], lacc[qs]);
      lacc[qs] = MFMA(onesf, pf[qs][1], lacc[qs]);
    }
#pragma unroll
    for (int dj = 0; dj < 4; dj++) {
      bfrag v0 = ldfrag(&Vs[(dj * 16 + c) * 64 + (quad ^ c7) * 8]);
      bfrag v1 = ldfrag(&Vs[(dj * 16 + c) * 64 + ((quad + 4) ^ c7) * 8]);
#pragma unroll
      for (int qs = 0; qs < 2; qs++) {
        oacc[qs][dj] = MFMA(v0, pf[qs][0], oacc[qs][dj]);
        oacc[qs][dj] = MFMA(v1, pf[qs][1], oacc[qs][dj]);
      }
    }
  }

  // O[q][h*64+d] = O^T / l ; pack 4 contiguous d -> 8B stores
#pragma unroll
  for (int qs = 0; qs < 2; qs++) {
    const float inv = 1.0f / lacc[qs][0];
    bf16* op =
        O + (size_t)(b * 1024 + qt * 128 + w * 32 + qs * 16 + c) * 1024 + h * 64 + quad * 4;
#pragma unroll
    for (int dj = 0; dj < 4; dj++) pack4_store(op + dj * 16, oacc[qs][dj], inv);
  }
}

// ---------------- launch ----------------

extern "C" void kernel_launch(void* const* d_in, const int* in_sizes, int n_in,
                              void* d_out, int out_size, void* d_ws, size_t ws_size,
                              hipStream_t stream) {
  const float* X  = (const float*)d_in[0];
  const float* rp = (const float*)d_in[1];
  const float* wq = (const float*)d_in[2];
  const float* bq = (const float*)d_in[3];
  const float* wk = (const float*)d_in[4];
  const float* bk = (const float*)d_in[5];
  const float* wv = (const float*)d_in[6];
  const float* bv = (const float*)d_in[7];
  const float* wo = (const float*)d_in[8];
  const float* bo = (const float*)d_in[9];
  float* out = (float*)d_out;

  char* ws = (char*)d_ws;
  const size_t MB = 1024 * 1024;
  bf16* Xb  = (bf16*)(ws + 0 * MB);    // 16 MB each
  bf16* Q   = (bf16*)(ws + 16 * MB);
  bf16* Kb  = (bf16*)(ws + 32 * MB);
  bf16* VT  = (bf16*)(ws + 48 * MB);   // [1024][8192]
  bf16* O   = (bf16*)(ws + 64 * MB);
  bf16* wqT = (bf16*)(ws + 80 * MB);   // 2 MB each; wqT+wkT contiguous = wqkT
  bf16* wkT = (bf16*)(ws + 82 * MB);
  bf16* wvT = (bf16*)(ws + 84 * MB);
  bf16* woT = (bf16*)(ws + 86 * MB);
  float* ctab = (float*)(ws + 88 * MB);  // 128 KB
  float* stab = ctab + 1024 * 32;        // 128 KB

  k_convert_x<<<dim3(8192), dim3(256), 0, stream>>>(X, (unsigned short*)Xb, rp, ctab, stab);
  k_transpose_w<<<dim3(16, 16, 4), dim3(256), 0, stream>>>(
      wq, wk, wv, wo, (unsigned short*)wqT, (unsigned short*)wkT, (unsigned short*)wvT,
      (unsigned short*)woT);
  k_gemm_qk<<<dim3(64, 16), dim3(256), 0, stream>>>(Xb, wqT, bq, bk, ctab, stab, Q, Kb);
  k_gemm_vt<<<dim3(64, 16), dim3(256), 0, stream>>>(wvT, Xb, bv, VT);
  k_flash<<<dim3(128, 8), dim3(256), 0, stream>>>(Q, Kb, VT, O);
  k_gemm_o<<<dim3(128, 8), dim3(256), 0, stream>>>(O, woT, bo, out);
}